// Round 11
// baseline (2239.326 us; speedup 1.0000x reference)
//
#include <hip/hip_runtime.h>
#include <math.h>

// Residual VQ, 4 stages, N=16384 rows, D=512, K=4096.
// Round 11: RECOVERY. Round-10's 256x128 passA regressed (72KB LDS -> 11%
// occupancy, MfmaUtil 9.8%). Revert passA to the proven round-9 128x128
// structure + T14 register prefetch (issue next chunk's global loads BEFORE
// compute so HBM/L2 latency hides under the 32 MFMAs). Keep round-10's
// swizzled passC (its conflict fix worked: dropped out of top-5).
// Exact-math invariants (verified rounds 3-10): one fmaf per d, d ascending,
// per output; epilogue fl(fl(rsq-fl(2*dot))+cbsq) uncontracted; first-index
// ties; numpy pairwise rsq/cbsq tree; exact residual/q_ste chain in combine.

namespace {
constexpr int N_ROWS     = 16384;
constexpr int DIM        = 512;
constexpr int K_CODES    = 4096;
constexpr int NUM_STAGES = 4;

constexpr int KTILES = 32;            // 128 codes per tile
constexpr int LTS    = 72;            // passA LDS row stride (bf16 elems)
constexpr float EPS  = 1e-3f;         // candidate margin (proven rounds 7-10)

constexpr int CROWS  = 64;            // passC rows per batch
constexpr int WSTRC  = 68;            // passC Ws row stride (dwords)
constexpr int RSTR   = 68;            // passC Rs row stride (dwords)

// d_out layout (all read back as float32):
constexpr size_t Q_OFF    = 0;
constexpr size_t IDX_OFF  = (size_t)N_ROWS * DIM;                  // 8388608
constexpr size_t LOSS_OFF = IDX_OFF + (size_t)N_ROWS * NUM_STAGES; // 8454144

// ws layout (bytes), total ~56.2 MB:
constexpr size_t RES_OFF  = 0;                                    // 32 MB fp32 residual
constexpr size_t RH_OFF   = (size_t)N_ROWS * DIM * 4;             // +16 MB bf16 residual
constexpr size_t WH_OFF   = RH_OFF + (size_t)N_ROWS * DIM * 2;    // +4 MB bf16 codebook
constexpr size_t CBSQ_OFF = WH_OFF + (size_t)K_CODES * DIM * 2;   // +16 KB
constexpr size_t RSQ_OFF  = CBSQ_OFF + (size_t)K_CODES * 4;       // +64 KB
constexpr size_t PART_OFF = RSQ_OFF + (size_t)N_ROWS * 4;         // +2 MB tile mins
constexpr size_t BCNT_OFF = PART_OFF + (size_t)N_ROWS * KTILES * 4; // +128 B
constexpr size_t BENT_OFF = BCNT_OFF + 128;                       // +2 MB worklists
constexpr size_t BEST_OFF = BENT_OFF + (size_t)KTILES * N_ROWS * 4; // +128 KB packed best
} // namespace

typedef short bf16x8 __attribute__((ext_vector_type(8)));
typedef float f32x4  __attribute__((ext_vector_type(4)));

__device__ __forceinline__ unsigned short f2bf(float x) {   // RNE fp32->bf16
    unsigned int u = __float_as_uint(x);
    return (unsigned short)((u + 0x7fffu + ((u >> 16) & 1u)) >> 16);
}

__device__ __forceinline__ float f4c(const float4& v, int q) {
    return q == 0 ? v.x : q == 1 ? v.y : q == 2 ? v.z : v.w;
}

// Register-based exact pairwise tree: v8[i] = row[lane + i*64], i=0..7.
// Returns the numpy fp32 pairwise sum of squares on lane 0.
__device__ __forceinline__ float rowsq_tree(const float v8[8], int lane) {
#pragma clang fp contract(off)
    float P[4];
#pragma unroll
    for (int b = 0; b < 4; ++b) {
        float xa = v8[2 * b];          // elem b*128 + lane
        float xb = v8[2 * b + 1];      // elem b*128 + 64 + lane
        float sa = xa * xa;
        float sb = xb * xb;
        float R  = sa + sb;
        float t  = R + __shfl_down(R, 16, 64);
        float u  = t + __shfl_down(t, 32, 64);
        float a  = u + __shfl_down(u, 8, 64);
        float c  = a + __shfl_down(a, 4, 64);
        float d  = c + __shfl_down(c, 2, 64);
        P[b]     = d + __shfl_down(d, 1, 64);
    }
    float s01 = P[0] + P[1];
    float s23 = P[2] + P[3];
    return s01 + s23;
}

__global__ __launch_bounds__(64)
void cbsq_kernel(const float* __restrict__ cb, float* __restrict__ cb_sq,
                 float* __restrict__ loss) {
    int k = blockIdx.x;
    int lane = threadIdx.x;
    const float* row = cb + (size_t)k * DIM;
    float v8[8];
#pragma unroll
    for (int i = 0; i < 8; ++i) v8[i] = row[lane + i * 64];
    float s = rowsq_tree(v8, lane);
    if (lane == 0) cb_sq[k] = s;
    if (k == 0 && lane == 0) *loss = 0.0f;
}

// Stage-0 init: rh = bf16(input), rsq = pairwise(input), zero bcnt.
__global__ __launch_bounds__(256)
void init_kernel(const float* __restrict__ input,
                 unsigned short* __restrict__ rh,
                 float* __restrict__ rsq, int* __restrict__ bcnt) {
    const int t = threadIdx.x;
    if (blockIdx.x == 0 && t < KTILES) bcnt[t] = 0;
    const int lane = t & 63;
    const int sub  = t >> 6;
    const int row  = blockIdx.x * 4 + sub;
    const float* x = input + (size_t)row * DIM;
    unsigned short* rhp = rh + (size_t)row * DIM;
    float v8[8];
#pragma unroll
    for (int i = 0; i < 8; ++i) {
        int d = lane + i * 64;
        float v = x[d];
        v8[i] = v;
        rhp[d] = f2bf(v);
    }
    float s = rowsq_tree(v8, lane);
    if (lane == 0) rsq[row] = s;
}

// fp32 codebook -> bf16 (RNE), once per launch.
__global__ __launch_bounds__(256)
void whcvt_kernel(const float* __restrict__ cb, unsigned short* __restrict__ wh) {
    size_t i = ((size_t)blockIdx.x * 256 + threadIdx.x) * 8;
    float4 v0 = *(const float4*)(cb + i);
    float4 v1 = *(const float4*)(cb + i + 4);
    uint4 o;
    o.x = f2bf(v0.x) | ((unsigned)f2bf(v0.y) << 16);
    o.y = f2bf(v0.z) | ((unsigned)f2bf(v0.w) << 16);
    o.z = f2bf(v1.x) | ((unsigned)f2bf(v1.y) << 16);
    o.w = f2bf(v1.z) | ((unsigned)f2bf(v1.w) << 16);
    *(uint4*)(wh + i) = o;
}

// Pass A: 128x128x(BK=64) bf16 MFMA GEMM; per-(row, ktile) min of y^.
// Round-9 tile/layout + T14 register prefetch of the next chunk.
__global__ __launch_bounds__(256, 1)
void passA_kernel(const unsigned short* __restrict__ rh,
                  const unsigned short* __restrict__ wh,
                  const float* __restrict__ cb_sq,
                  const float* __restrict__ rsq,
                  float* __restrict__ part) {
    const int jb = blockIdx.x;              // ktile (fast: share A-panel in L2)
    const int mb = blockIdx.y;
    const int mbase = mb * 128;
    const int nbase = jb * 128;

    __shared__ __align__(16) unsigned short At[128 * LTS];   // 18.4 KB
    __shared__ __align__(16) unsigned short Bt[128 * LTS];   // 18.4 KB
    __shared__ float rowmin[128][2];                         // 1 KB

    const int t    = threadIdx.x;
    const int lane = t & 63;
    const int wid  = t >> 6;
    const int wr   = wid >> 1;              // wave row (0/1)
    const int wc   = wid & 1;               // wave col (0/1)

    f32x4 acc[4][4];
#pragma unroll
    for (int mi = 0; mi < 4; ++mi)
#pragma unroll
        for (int ni = 0; ni < 4; ++ni) acc[mi][ni] = (f32x4){0.f, 0.f, 0.f, 0.f};

    // Staging: A and B each 128 rows x 64 d bf16 = 1024 uint4 -> 4/thread each.
    // idx = p*256 + t: row = idx>>3 (0..127), d8 = idx&7.
    uint4 aS[4], bS[4];

#define PA_LOAD(c)                                                            \
    {                                                                         \
        _Pragma("unroll")                                                     \
        for (int p = 0; p < 4; ++p) {                                         \
            int idx = p * 256 + t;                                            \
            int row = idx >> 3;                                               \
            int d8  = idx & 7;                                                \
            aS[p] = *(const uint4*)(rh + (size_t)(mbase + row) * DIM          \
                                    + (c) * 64 + d8 * 8);                     \
            bS[p] = *(const uint4*)(wh + (size_t)(nbase + row) * DIM          \
                                    + (c) * 64 + d8 * 8);                     \
        }                                                                     \
    }

#define PA_STORE()                                                            \
    {                                                                         \
        _Pragma("unroll")                                                     \
        for (int p = 0; p < 4; ++p) {                                         \
            int idx = p * 256 + t;                                            \
            int row = idx >> 3;                                               \
            int d8  = idx & 7;                                                \
            *(uint4*)&At[row * LTS + d8 * 8] = aS[p];                         \
            *(uint4*)&Bt[row * LTS + d8 * 8] = bS[p];                         \
        }                                                                     \
    }

    PA_LOAD(0);
    for (int c = 0; c < DIM / 64; ++c) {
        PA_STORE();                          // c>0: previous compute done (barrier below)
        __syncthreads();
        if (c + 1 < DIM / 64) PA_LOAD(c + 1);   // issue early; drains under MFMAs

#pragma unroll
        for (int kk = 0; kk < 2; ++kk) {
            bf16x8 af[4], bfr[4];
#pragma unroll
            for (int mi = 0; mi < 4; ++mi)
                af[mi] = *(const bf16x8*)&At[(wr * 64 + mi * 16 + (lane & 15)) * LTS
                                             + kk * 32 + (lane >> 4) * 8];
#pragma unroll
            for (int ni = 0; ni < 4; ++ni)
                bfr[ni] = *(const bf16x8*)&Bt[(wc * 64 + ni * 16 + (lane & 15)) * LTS
                                              + kk * 32 + (lane >> 4) * 8];
#pragma unroll
            for (int mi = 0; mi < 4; ++mi)
#pragma unroll
                for (int ni = 0; ni < 4; ++ni)
                    acc[mi][ni] = __builtin_amdgcn_mfma_f32_16x16x32_bf16(
                        af[mi], bfr[ni], acc[mi][ni], 0, 0, 0);
        }
        __syncthreads();                     // reads done before next STORE
    }

    // Epilogue: y^ rounding-form, min over wave's 64 cols per row, cross-wave min.
#pragma unroll
    for (int mi = 0; mi < 4; ++mi) {
#pragma unroll
        for (int reg = 0; reg < 4; ++reg) {
            int rloc = wr * 64 + mi * 16 + (lane >> 4) * 4 + reg;
            float rsqv = rsq[mbase + rloc];
            float m = INFINITY;
#pragma unroll
            for (int ni = 0; ni < 4; ++ni) {
                int kg = nbase + wc * 64 + ni * 16 + (lane & 15);
                float y;
                {
#pragma clang fp contract(off)
                    float t2 = 2.0f * acc[mi][ni][reg];
                    float u  = rsqv - t2;
                    y        = u + cb_sq[kg];
                }
                m = fminf(m, y);
            }
#pragma unroll
            for (int off = 1; off < 16; off <<= 1)
                m = fminf(m, __shfl_xor(m, off, 64));
            if ((lane & 15) == 0) rowmin[rloc][wc] = m;
        }
    }
    __syncthreads();
    if (t < 128)
        part[(size_t)(mbase + t) * KTILES + jb] = fminf(rowmin[t][0], rowmin[t][1]);
}

// Pass B: per row, flag tiles within EPS of the global min; init best.
__global__ __launch_bounds__(256)
void passB_kernel(const float* __restrict__ part,
                  int* __restrict__ bcnt, int* __restrict__ bent,
                  unsigned long long* __restrict__ best) {
    int row = blockIdx.x * 256 + threadIdx.x;
    const float* p = part + (size_t)row * KTILES;
    float gmin = p[0];
#pragma unroll
    for (int j = 1; j < KTILES; ++j) gmin = fminf(gmin, p[j]);
    float thr = gmin + EPS;
    best[row] = ~0ull;
#pragma unroll
    for (int j = 0; j < KTILES; ++j) {
        if (p[j] <= thr) {
            int pos = atomicAdd(&bcnt[j], 1);
            bent[(size_t)j * N_ROWS + pos] = row;
        }
    }
}

// Pass C: exact recheck (round-10 version, conflict-free swizzle). 256 thr =
// 8 row-groups x 32 cand-groups; thread owns 8 rows x 4 cands. Ws row-major
// with XOR-swizzled float4 slots (slot = d4 ^ ((cand>>2)&7)).
// Chain order d = 0..511 ascending per pair -> bit-exact.
__global__ __launch_bounds__(256)
void passC_kernel(const float* __restrict__ res,
                  const float* __restrict__ cb,
                  const float* __restrict__ cb_sq,
                  const float* __restrict__ rsq,
                  const int* __restrict__ bcnt, const int* __restrict__ bent,
                  unsigned long long* __restrict__ best) {
    const int j   = blockIdx.x;             // ktile
    const int cnt = bcnt[j];
    const int t   = threadIdx.x;
    const int cg  = t & 31;                 // cands cg*4 .. cg*4+3
    const int rg  = t >> 5;                 // rows  rg*8 .. rg*8+7

    __shared__ __align__(16) float Ws[128 * WSTRC];   // 34.8 KB, swizzled
    __shared__ __align__(16) float Rs[CROWS * RSTR];  // 17.4 KB
    __shared__ int   rowl[CROWS];
    __shared__ float rsql[CROWS];

    for (int base = blockIdx.y * CROWS; base < cnt; base += gridDim.y * CROWS) {
        if (t < CROWS) {
            int e  = base + t;
            int rw = bent[(size_t)j * N_ROWS + (e < cnt ? e : cnt - 1)];
            rowl[t] = rw;
            rsql[t] = rsq[rw];
        }
        __syncthreads();
        const int nrows = min(CROWS, cnt - base);

        float acc[8][4];
#pragma unroll
        for (int ri = 0; ri < 8; ++ri)
#pragma unroll
            for (int q = 0; q < 4; ++q) acc[ri][q] = 0.0f;

        for (int d0 = 0; d0 < DIM; d0 += 64) {
            // Stage W: 128 cands x 64 d = 2048 float4 -> 8/thread, swizzled slot.
#pragma unroll
            for (int p = 0; p < 8; ++p) {
                int idx  = p * 256 + t;
                int cand = idx >> 4;
                int d4   = idx & 15;
                float4 v = *(const float4*)(cb + (size_t)(j * 128 + cand) * DIM + d0 + d4 * 4);
                int s = d4 ^ ((cand >> 2) & 7);
                *(float4*)&Ws[cand * WSTRC + s * 4] = v;
            }
            // Stage R: 64 rows x 64 d = 1024 float4 -> 4/thread, row-major.
#pragma unroll
            for (int p = 0; p < 4; ++p) {
                int idx = p * 256 + t;
                int row = idx >> 4;
                int d4  = idx & 15;
                float4 v = *(const float4*)(res + (size_t)rowl[row] * DIM + d0 + d4 * 4);
                *(float4*)&Rs[row * RSTR + d4 * 4] = v;
            }
            __syncthreads();

            // 16 d-quads: per dq, 4 Ws reads (cand rows) + 8 Rs reads (broadcast).
#pragma unroll
            for (int dq = 0; dq < 16; ++dq) {
                const int s = dq ^ (cg & 7);   // (cand>>2)&7 == cg&7 for our cands
                float4 w4[4];
#pragma unroll
                for (int q = 0; q < 4; ++q)
                    w4[q] = *(const float4*)&Ws[(cg * 4 + q) * WSTRC + s * 4];
#pragma unroll
                for (int ri = 0; ri < 8; ++ri) {
                    float4 rf = *(const float4*)&Rs[(rg * 8 + ri) * RSTR + dq * 4];
#pragma unroll
                    for (int dd = 0; dd < 4; ++dd) {
                        float rv = f4c(rf, dd);
                        acc[ri][0] = fmaf(rv, f4c(w4[0], dd), acc[ri][0]);
                        acc[ri][1] = fmaf(rv, f4c(w4[1], dd), acc[ri][1]);
                        acc[ri][2] = fmaf(rv, f4c(w4[2], dd), acc[ri][2]);
                        acc[ri][3] = fmaf(rv, f4c(w4[3], dd), acc[ri][3]);
                    }
                }
            }
            __syncthreads();
        }

        // Epilogue: exact y, lexicographic (y,k) reduce over the 32 cand-lanes.
#pragma unroll
        for (int ri = 0; ri < 8; ++ri) {
            int rloc = rg * 8 + ri;
            float rsqv = rsql[rloc];
            float by = INFINITY; int bk = 0x7fffffff;
#pragma unroll
            for (int q = 0; q < 4; ++q) {
                int k = j * 128 + cg * 4 + q;
                float y;
                {
#pragma clang fp contract(off)
                    float t2 = 2.0f * acc[ri][q];
                    float u  = rsqv - t2;
                    y        = u + cb_sq[k];
                }
                if (y < by || (y == by && k < bk)) { by = y; bk = k; }
            }
#pragma unroll
            for (int off = 1; off < 32; off <<= 1) {   // cg = lane bits 0..4
                float ov = __shfl_xor(by, off, 64);
                int   oi = __shfl_xor(bk, off, 64);
                if (ov < by || (ov == by && oi < bk)) { by = ov; bk = oi; }
            }
            if (cg == 0 && rloc < nrows) {
                unsigned long long pk =
                    ((unsigned long long)__float_as_uint(by) << 32) |
                    (unsigned long long)(unsigned)bk;
                atomicMin(&best[rowl[rloc]], pk);
            }
        }
        __syncthreads();   // before next batch overwrites rowl/rsql
    }
}

// Combine: best index -> idx_out; exact fp32 residual/q_ste update; for the
// next stage also emit bf16 residual (rh), exact pairwise rsq, and zero bcnt.
__global__ __launch_bounds__(256)
void combine_kernel(float* __restrict__ res_out,
                    const float* __restrict__ res_in,
                    const float* __restrict__ cb,
                    const unsigned long long* __restrict__ best,
                    float* __restrict__ qout,
                    float* __restrict__ idx_out,
                    unsigned short* __restrict__ rh,
                    float* __restrict__ rsq,
                    int* __restrict__ bcnt,
                    int stage, int do_next) {
#pragma clang fp contract(off)
    const int t    = threadIdx.x;
    if (do_next && blockIdx.x == 0 && t < KTILES) bcnt[t] = 0;
    const int lane = t & 63;
    const int sub  = t >> 6;
    const int row  = blockIdx.x * 4 + sub;

    int bi = (int)(best[row] & 0xffffffffull);
    if (lane == 0) idx_out[(size_t)row * NUM_STAGES + stage] = (float)bi;

    const float* w   = cb + (size_t)bi * DIM;
    const float* rin = res_in + (size_t)row * DIM;
    float*       r   = res_out + (size_t)row * DIM;
    float*       q   = qout + (size_t)row * DIM;
    unsigned short* rhp = rh + (size_t)row * DIM;

    float rn8[8];
#pragma unroll
    for (int i = 0; i < DIM / 64; ++i) {
        int d = lane + i * 64;
        float wv = w[d];
        float rv = rin[d];
        float tq    = wv - rv;     // fl(q - r)
        float q_ste = rv + tq;     // fl(r + (q - r))
        float rn    = rv - q_ste;  // fl(r - q_ste)
        rn8[i] = rn;
        if (do_next) {
            r[d]   = rn;
            rhp[d] = f2bf(rn);
        }
        if (stage == 0) q[d] = q_ste;
        else            q[d] = q[d] + q_ste;   // stage-order fp32 accumulation
    }
    if (do_next) {
        float s = rowsq_tree(rn8, lane);
        if (lane == 0) rsq[row] = s;
    }
}

extern "C" void kernel_launch(void* const* d_in, const int* in_sizes, int n_in,
                              void* d_out, int out_size, void* d_ws, size_t ws_size,
                              hipStream_t stream) {
    const float* input = (const float*)d_in[0];
    const float* cb    = (const float*)d_in[1];

    float* out_f   = (float*)d_out;
    float* qout    = out_f + Q_OFF;
    float* idx_out = out_f + IDX_OFF;
    float* loss    = out_f + LOSS_OFF;

    char* ws = (char*)d_ws;
    float*          residual = (float*)(ws + RES_OFF);
    unsigned short* rh       = (unsigned short*)(ws + RH_OFF);
    unsigned short* wh       = (unsigned short*)(ws + WH_OFF);
    float*          cb_sq    = (float*)(ws + CBSQ_OFF);
    float*          rsq      = (float*)(ws + RSQ_OFF);
    float*          part     = (float*)(ws + PART_OFF);
    int*            bcnt     = (int*)(ws + BCNT_OFF);
    int*            bent     = (int*)(ws + BENT_OFF);
    unsigned long long* best = (unsigned long long*)(ws + BEST_OFF);

    whcvt_kernel<<<(K_CODES * DIM) / (256 * 8), 256, 0, stream>>>(cb, wh);
    cbsq_kernel<<<K_CODES, 64, 0, stream>>>(cb, cb_sq, loss);
    init_kernel<<<N_ROWS / 4, 256, 0, stream>>>(input, rh, rsq, bcnt);

    for (int s = 0; s < NUM_STAGES; ++s) {
        const float* rin = (s == 0) ? input : residual;
        passA_kernel<<<dim3(KTILES, N_ROWS / 128), 256, 0, stream>>>(
            rh, wh, cb_sq, rsq, part);
        passB_kernel<<<N_ROWS / 256, 256, 0, stream>>>(part, bcnt, bent, best);
        passC_kernel<<<dim3(KTILES, 16), 256, 0, stream>>>(
            rin, cb, cb_sq, rsq, bcnt, bent, best);
        combine_kernel<<<N_ROWS / 4, 256, 0, stream>>>(
            residual, rin, cb, best, qout, idx_out, rh, rsq, bcnt,
            s, (s < NUM_STAGES - 1) ? 1 : 0);
    }
}

// Round 12
// 1378.703 us; speedup vs baseline: 1.6242x; 1.6242x over previous
//
#include <hip/hip_runtime.h>
#include <math.h>

// Residual VQ, 4 stages, N=16384 rows, D=512, K=4096.
// Round 12: RECOVERY-2. Round-11's register-prefetch passA spilled (WRITE_SIZE
// 410MB/dispatch at VGPR=100): holding 8 uint4 staging regs across the MFMA
// block is not compiler-controllable at HIP level. Full revert of passA to the
// round-9 verbatim kernel (98.7us, MfmaUtil 30%, VGPR 64, no spill). Keep
// round-10/11 passC (swizzled Ws, CROWS=64 -- proven: out of top-5 twice).
// This is the first bench of best-known passA + best-known passC together.
// Exact-math invariants (verified rounds 3-11): one fmaf per d, d ascending,
// per output; epilogue fl(fl(rsq-fl(2*dot))+cbsq) uncontracted; first-index
// ties; numpy pairwise rsq/cbsq tree; exact residual/q_ste chain in combine.

namespace {
constexpr int N_ROWS     = 16384;
constexpr int DIM        = 512;
constexpr int K_CODES    = 4096;
constexpr int NUM_STAGES = 4;

constexpr int KTILES = 32;            // 128 codes per tile
constexpr int LTS    = 72;            // passA LDS row stride (bf16 elems)
constexpr float EPS  = 1e-3f;         // candidate margin (proven rounds 7-11)

constexpr int CROWS  = 64;            // passC rows per batch
constexpr int WSTRC  = 68;            // passC Ws row stride (dwords)
constexpr int RSTR   = 68;            // passC Rs row stride (dwords)

// d_out layout (all read back as float32):
constexpr size_t Q_OFF    = 0;
constexpr size_t IDX_OFF  = (size_t)N_ROWS * DIM;                  // 8388608
constexpr size_t LOSS_OFF = IDX_OFF + (size_t)N_ROWS * NUM_STAGES; // 8454144

// ws layout (bytes), total ~56.2 MB:
constexpr size_t RES_OFF  = 0;                                    // 32 MB fp32 residual
constexpr size_t RH_OFF   = (size_t)N_ROWS * DIM * 4;             // +16 MB bf16 residual
constexpr size_t WH_OFF   = RH_OFF + (size_t)N_ROWS * DIM * 2;    // +4 MB bf16 codebook
constexpr size_t CBSQ_OFF = WH_OFF + (size_t)K_CODES * DIM * 2;   // +16 KB
constexpr size_t RSQ_OFF  = CBSQ_OFF + (size_t)K_CODES * 4;       // +64 KB
constexpr size_t PART_OFF = RSQ_OFF + (size_t)N_ROWS * 4;         // +2 MB tile mins
constexpr size_t BCNT_OFF = PART_OFF + (size_t)N_ROWS * KTILES * 4; // +128 B
constexpr size_t BENT_OFF = BCNT_OFF + 128;                       // +2 MB worklists
constexpr size_t BEST_OFF = BENT_OFF + (size_t)KTILES * N_ROWS * 4; // +128 KB packed best
} // namespace

typedef short bf16x8 __attribute__((ext_vector_type(8)));
typedef float f32x4  __attribute__((ext_vector_type(4)));

__device__ __forceinline__ unsigned short f2bf(float x) {   // RNE fp32->bf16
    unsigned int u = __float_as_uint(x);
    return (unsigned short)((u + 0x7fffu + ((u >> 16) & 1u)) >> 16);
}

__device__ __forceinline__ float f4c(const float4& v, int q) {
    return q == 0 ? v.x : q == 1 ? v.y : q == 2 ? v.z : v.w;
}

// Register-based exact pairwise tree: v8[i] = row[lane + i*64], i=0..7.
// Returns the numpy fp32 pairwise sum of squares on lane 0.
__device__ __forceinline__ float rowsq_tree(const float v8[8], int lane) {
#pragma clang fp contract(off)
    float P[4];
#pragma unroll
    for (int b = 0; b < 4; ++b) {
        float xa = v8[2 * b];          // elem b*128 + lane
        float xb = v8[2 * b + 1];      // elem b*128 + 64 + lane
        float sa = xa * xa;
        float sb = xb * xb;
        float R  = sa + sb;
        float t  = R + __shfl_down(R, 16, 64);
        float u  = t + __shfl_down(t, 32, 64);
        float a  = u + __shfl_down(u, 8, 64);
        float c  = a + __shfl_down(a, 4, 64);
        float d  = c + __shfl_down(c, 2, 64);
        P[b]     = d + __shfl_down(d, 1, 64);
    }
    float s01 = P[0] + P[1];
    float s23 = P[2] + P[3];
    return s01 + s23;
}

__global__ __launch_bounds__(64)
void cbsq_kernel(const float* __restrict__ cb, float* __restrict__ cb_sq,
                 float* __restrict__ loss) {
    int k = blockIdx.x;
    int lane = threadIdx.x;
    const float* row = cb + (size_t)k * DIM;
    float v8[8];
#pragma unroll
    for (int i = 0; i < 8; ++i) v8[i] = row[lane + i * 64];
    float s = rowsq_tree(v8, lane);
    if (lane == 0) cb_sq[k] = s;
    if (k == 0 && lane == 0) *loss = 0.0f;
}

// Stage-0 init: rh = bf16(input), rsq = pairwise(input), zero bcnt.
__global__ __launch_bounds__(256)
void init_kernel(const float* __restrict__ input,
                 unsigned short* __restrict__ rh,
                 float* __restrict__ rsq, int* __restrict__ bcnt) {
    const int t = threadIdx.x;
    if (blockIdx.x == 0 && t < KTILES) bcnt[t] = 0;
    const int lane = t & 63;
    const int sub  = t >> 6;
    const int row  = blockIdx.x * 4 + sub;
    const float* x = input + (size_t)row * DIM;
    unsigned short* rhp = rh + (size_t)row * DIM;
    float v8[8];
#pragma unroll
    for (int i = 0; i < 8; ++i) {
        int d = lane + i * 64;
        float v = x[d];
        v8[i] = v;
        rhp[d] = f2bf(v);
    }
    float s = rowsq_tree(v8, lane);
    if (lane == 0) rsq[row] = s;
}

// fp32 codebook -> bf16 (RNE), once per launch.
__global__ __launch_bounds__(256)
void whcvt_kernel(const float* __restrict__ cb, unsigned short* __restrict__ wh) {
    size_t i = ((size_t)blockIdx.x * 256 + threadIdx.x) * 8;
    float4 v0 = *(const float4*)(cb + i);
    float4 v1 = *(const float4*)(cb + i + 4);
    uint4 o;
    o.x = f2bf(v0.x) | ((unsigned)f2bf(v0.y) << 16);
    o.y = f2bf(v0.z) | ((unsigned)f2bf(v0.w) << 16);
    o.z = f2bf(v1.x) | ((unsigned)f2bf(v1.y) << 16);
    o.w = f2bf(v1.z) | ((unsigned)f2bf(v1.w) << 16);
    *(uint4*)(wh + i) = o;
}

// Pass A: 128x128x(BK=64) bf16 MFMA GEMM; per-(row, ktile) min of y^.
// ROUND-9 VERBATIM (98.7us, MfmaUtil 30%, VGPR 64, no spill).
__global__ __launch_bounds__(256, 2)
void passA_kernel(const unsigned short* __restrict__ rh,
                  const unsigned short* __restrict__ wh,
                  const float* __restrict__ cb_sq,
                  const float* __restrict__ rsq,
                  float* __restrict__ part) {
    const int jb = blockIdx.x;              // ktile (fast: share A-panel in L2)
    const int mb = blockIdx.y;
    const int mbase = mb * 128;
    const int nbase = jb * 128;

    __shared__ __align__(16) unsigned short At[128 * LTS];
    __shared__ __align__(16) unsigned short Bt[128 * LTS];
    __shared__ float rowmin[128][2];

    const int t    = threadIdx.x;
    const int lane = t & 63;
    const int wid  = t >> 6;
    const int wr   = wid >> 1;              // wave row (0/1)
    const int wc   = wid & 1;               // wave col (0/1)

    f32x4 acc[4][4];
#pragma unroll
    for (int mi = 0; mi < 4; ++mi)
#pragma unroll
        for (int ni = 0; ni < 4; ++ni) acc[mi][ni] = (f32x4){0.f, 0.f, 0.f, 0.f};

    for (int k0 = 0; k0 < DIM; k0 += 64) {
        // Stage A and B: each 128 rows x 64 d bf16 = 4 rounds x (16B ld + 16B st).
#pragma unroll
        for (int p = 0; p < 4; ++p) {
            int idx = p * 256 + t;
            int row = idx >> 3;
            int d8  = idx & 7;
            uint4 va = *(const uint4*)(rh + (size_t)(mbase + row) * DIM + k0 + d8 * 8);
            *(uint4*)&At[row * LTS + d8 * 8] = va;
            uint4 vb = *(const uint4*)(wh + (size_t)(nbase + row) * DIM + k0 + d8 * 8);
            *(uint4*)&Bt[row * LTS + d8 * 8] = vb;
        }
        __syncthreads();

#pragma unroll
        for (int kk = 0; kk < 2; ++kk) {
            bf16x8 af[4], bfr[4];
#pragma unroll
            for (int mi = 0; mi < 4; ++mi)
                af[mi] = *(const bf16x8*)&At[(wr * 64 + mi * 16 + (lane & 15)) * LTS
                                             + kk * 32 + (lane >> 4) * 8];
#pragma unroll
            for (int ni = 0; ni < 4; ++ni)
                bfr[ni] = *(const bf16x8*)&Bt[(wc * 64 + ni * 16 + (lane & 15)) * LTS
                                              + kk * 32 + (lane >> 4) * 8];
#pragma unroll
            for (int mi = 0; mi < 4; ++mi)
#pragma unroll
                for (int ni = 0; ni < 4; ++ni)
                    acc[mi][ni] = __builtin_amdgcn_mfma_f32_16x16x32_bf16(
                        af[mi], bfr[ni], acc[mi][ni], 0, 0, 0);
        }
        __syncthreads();
    }

    // Epilogue: y^ rounding-form, min over wave's 64 cols per row, cross-wave min.
#pragma unroll
    for (int mi = 0; mi < 4; ++mi) {
#pragma unroll
        for (int reg = 0; reg < 4; ++reg) {
            int rloc = wr * 64 + mi * 16 + (lane >> 4) * 4 + reg;
            float rsqv = rsq[mbase + rloc];
            float m = INFINITY;
#pragma unroll
            for (int ni = 0; ni < 4; ++ni) {
                int kg = nbase + wc * 64 + ni * 16 + (lane & 15);
                float y;
                {
#pragma clang fp contract(off)
                    float t2 = 2.0f * acc[mi][ni][reg];
                    float u  = rsqv - t2;
                    y        = u + cb_sq[kg];
                }
                m = fminf(m, y);
            }
#pragma unroll
            for (int off = 1; off < 16; off <<= 1)
                m = fminf(m, __shfl_xor(m, off, 64));
            if ((lane & 15) == 0) rowmin[rloc][wc] = m;
        }
    }
    __syncthreads();
    if (t < 128)
        part[(size_t)(mbase + t) * KTILES + jb] = fminf(rowmin[t][0], rowmin[t][1]);
}

// Pass B: per row, flag tiles within EPS of the global min; init best.
__global__ __launch_bounds__(256)
void passB_kernel(const float* __restrict__ part,
                  int* __restrict__ bcnt, int* __restrict__ bent,
                  unsigned long long* __restrict__ best) {
    int row = blockIdx.x * 256 + threadIdx.x;
    const float* p = part + (size_t)row * KTILES;
    float gmin = p[0];
#pragma unroll
    for (int j = 1; j < KTILES; ++j) gmin = fminf(gmin, p[j]);
    float thr = gmin + EPS;
    best[row] = ~0ull;
#pragma unroll
    for (int j = 0; j < KTILES; ++j) {
        if (p[j] <= thr) {
            int pos = atomicAdd(&bcnt[j], 1);
            bent[(size_t)j * N_ROWS + pos] = row;
        }
    }
}

// Pass C: exact recheck (round-10/11 version, conflict-free swizzle). 256 thr =
// 8 row-groups x 32 cand-groups; thread owns 8 rows x 4 cands. Ws row-major
// with XOR-swizzled float4 slots (slot = d4 ^ ((cand>>2)&7)).
// Chain order d = 0..511 ascending per pair -> bit-exact.
__global__ __launch_bounds__(256)
void passC_kernel(const float* __restrict__ res,
                  const float* __restrict__ cb,
                  const float* __restrict__ cb_sq,
                  const float* __restrict__ rsq,
                  const int* __restrict__ bcnt, const int* __restrict__ bent,
                  unsigned long long* __restrict__ best) {
    const int j   = blockIdx.x;             // ktile
    const int cnt = bcnt[j];
    const int t   = threadIdx.x;
    const int cg  = t & 31;                 // cands cg*4 .. cg*4+3
    const int rg  = t >> 5;                 // rows  rg*8 .. rg*8+7

    __shared__ __align__(16) float Ws[128 * WSTRC];   // 34.8 KB, swizzled
    __shared__ __align__(16) float Rs[CROWS * RSTR];  // 17.4 KB
    __shared__ int   rowl[CROWS];
    __shared__ float rsql[CROWS];

    for (int base = blockIdx.y * CROWS; base < cnt; base += gridDim.y * CROWS) {
        if (t < CROWS) {
            int e  = base + t;
            int rw = bent[(size_t)j * N_ROWS + (e < cnt ? e : cnt - 1)];
            rowl[t] = rw;
            rsql[t] = rsq[rw];
        }
        __syncthreads();
        const int nrows = min(CROWS, cnt - base);

        float acc[8][4];
#pragma unroll
        for (int ri = 0; ri < 8; ++ri)
#pragma unroll
            for (int q = 0; q < 4; ++q) acc[ri][q] = 0.0f;

        for (int d0 = 0; d0 < DIM; d0 += 64) {
            // Stage W: 128 cands x 64 d = 2048 float4 -> 8/thread, swizzled slot.
#pragma unroll
            for (int p = 0; p < 8; ++p) {
                int idx  = p * 256 + t;
                int cand = idx >> 4;
                int d4   = idx & 15;
                float4 v = *(const float4*)(cb + (size_t)(j * 128 + cand) * DIM + d0 + d4 * 4);
                int s = d4 ^ ((cand >> 2) & 7);
                *(float4*)&Ws[cand * WSTRC + s * 4] = v;
            }
            // Stage R: 64 rows x 64 d = 1024 float4 -> 4/thread, row-major.
#pragma unroll
            for (int p = 0; p < 4; ++p) {
                int idx = p * 256 + t;
                int row = idx >> 4;
                int d4  = idx & 15;
                float4 v = *(const float4*)(res + (size_t)rowl[row] * DIM + d0 + d4 * 4);
                *(float4*)&Rs[row * RSTR + d4 * 4] = v;
            }
            __syncthreads();

            // 16 d-quads: per dq, 4 Ws reads (cand rows) + 8 Rs reads (broadcast).
#pragma unroll
            for (int dq = 0; dq < 16; ++dq) {
                const int s = dq ^ (cg & 7);   // (cand>>2)&7 == cg&7 for our cands
                float4 w4[4];
#pragma unroll
                for (int q = 0; q < 4; ++q)
                    w4[q] = *(const float4*)&Ws[(cg * 4 + q) * WSTRC + s * 4];
#pragma unroll
                for (int ri = 0; ri < 8; ++ri) {
                    float4 rf = *(const float4*)&Rs[(rg * 8 + ri) * RSTR + dq * 4];
#pragma unroll
                    for (int dd = 0; dd < 4; ++dd) {
                        float rv = f4c(rf, dd);
                        acc[ri][0] = fmaf(rv, f4c(w4[0], dd), acc[ri][0]);
                        acc[ri][1] = fmaf(rv, f4c(w4[1], dd), acc[ri][1]);
                        acc[ri][2] = fmaf(rv, f4c(w4[2], dd), acc[ri][2]);
                        acc[ri][3] = fmaf(rv, f4c(w4[3], dd), acc[ri][3]);
                    }
                }
            }
            __syncthreads();
        }

        // Epilogue: exact y, lexicographic (y,k) reduce over the 32 cand-lanes.
#pragma unroll
        for (int ri = 0; ri < 8; ++ri) {
            int rloc = rg * 8 + ri;
            float rsqv = rsql[rloc];
            float by = INFINITY; int bk = 0x7fffffff;
#pragma unroll
            for (int q = 0; q < 4; ++q) {
                int k = j * 128 + cg * 4 + q;
                float y;
                {
#pragma clang fp contract(off)
                    float t2 = 2.0f * acc[ri][q];
                    float u  = rsqv - t2;
                    y        = u + cb_sq[k];
                }
                if (y < by || (y == by && k < bk)) { by = y; bk = k; }
            }
#pragma unroll
            for (int off = 1; off < 32; off <<= 1) {   // cg = lane bits 0..4
                float ov = __shfl_xor(by, off, 64);
                int   oi = __shfl_xor(bk, off, 64);
                if (ov < by || (ov == by && oi < bk)) { by = ov; bk = oi; }
            }
            if (cg == 0 && rloc < nrows) {
                unsigned long long pk =
                    ((unsigned long long)__float_as_uint(by) << 32) |
                    (unsigned long long)(unsigned)bk;
                atomicMin(&best[rowl[rloc]], pk);
            }
        }
        __syncthreads();   // before next batch overwrites rowl/rsql
    }
}

// Combine: best index -> idx_out; exact fp32 residual/q_ste update; for the
// next stage also emit bf16 residual (rh), exact pairwise rsq, and zero bcnt.
__global__ __launch_bounds__(256)
void combine_kernel(float* __restrict__ res_out,
                    const float* __restrict__ res_in,
                    const float* __restrict__ cb,
                    const unsigned long long* __restrict__ best,
                    float* __restrict__ qout,
                    float* __restrict__ idx_out,
                    unsigned short* __restrict__ rh,
                    float* __restrict__ rsq,
                    int* __restrict__ bcnt,
                    int stage, int do_next) {
#pragma clang fp contract(off)
    const int t    = threadIdx.x;
    if (do_next && blockIdx.x == 0 && t < KTILES) bcnt[t] = 0;
    const int lane = t & 63;
    const int sub  = t >> 6;
    const int row  = blockIdx.x * 4 + sub;

    int bi = (int)(best[row] & 0xffffffffull);
    if (lane == 0) idx_out[(size_t)row * NUM_STAGES + stage] = (float)bi;

    const float* w   = cb + (size_t)bi * DIM;
    const float* rin = res_in + (size_t)row * DIM;
    float*       r   = res_out + (size_t)row * DIM;
    float*       q   = qout + (size_t)row * DIM;
    unsigned short* rhp = rh + (size_t)row * DIM;

    float rn8[8];
#pragma unroll
    for (int i = 0; i < DIM / 64; ++i) {
        int d = lane + i * 64;
        float wv = w[d];
        float rv = rin[d];
        float tq    = wv - rv;     // fl(q - r)
        float q_ste = rv + tq;     // fl(r + (q - r))
        float rn    = rv - q_ste;  // fl(r - q_ste)
        rn8[i] = rn;
        if (do_next) {
            r[d]   = rn;
            rhp[d] = f2bf(rn);
        }
        if (stage == 0) q[d] = q_ste;
        else            q[d] = q[d] + q_ste;   // stage-order fp32 accumulation
    }
    if (do_next) {
        float s = rowsq_tree(rn8, lane);
        if (lane == 0) rsq[row] = s;
    }
}

extern "C" void kernel_launch(void* const* d_in, const int* in_sizes, int n_in,
                              void* d_out, int out_size, void* d_ws, size_t ws_size,
                              hipStream_t stream) {
    const float* input = (const float*)d_in[0];
    const float* cb    = (const float*)d_in[1];

    float* out_f   = (float*)d_out;
    float* qout    = out_f + Q_OFF;
    float* idx_out = out_f + IDX_OFF;
    float* loss    = out_f + LOSS_OFF;

    char* ws = (char*)d_ws;
    float*          residual = (float*)(ws + RES_OFF);
    unsigned short* rh       = (unsigned short*)(ws + RH_OFF);
    unsigned short* wh       = (unsigned short*)(ws + WH_OFF);
    float*          cb_sq    = (float*)(ws + CBSQ_OFF);
    float*          rsq      = (float*)(ws + RSQ_OFF);
    float*          part     = (float*)(ws + PART_OFF);
    int*            bcnt     = (int*)(ws + BCNT_OFF);
    int*            bent     = (int*)(ws + BENT_OFF);
    unsigned long long* best = (unsigned long long*)(ws + BEST_OFF);

    whcvt_kernel<<<(K_CODES * DIM) / (256 * 8), 256, 0, stream>>>(cb, wh);
    cbsq_kernel<<<K_CODES, 64, 0, stream>>>(cb, cb_sq, loss);
    init_kernel<<<N_ROWS / 4, 256, 0, stream>>>(input, rh, rsq, bcnt);

    for (int s = 0; s < NUM_STAGES; ++s) {
        const float* rin = (s == 0) ? input : residual;
        passA_kernel<<<dim3(KTILES, N_ROWS / 128), 256, 0, stream>>>(
            rh, wh, cb_sq, rsq, part);
        passB_kernel<<<N_ROWS / 256, 256, 0, stream>>>(part, bcnt, bent, best);
        passC_kernel<<<dim3(KTILES, 16), 256, 0, stream>>>(
            rin, cb, cb_sq, rsq, bcnt, bent, best);
        combine_kernel<<<N_ROWS / 4, 256, 0, stream>>>(
            residual, rin, cb, best, qout, idx_out, rh, rsq, bcnt,
            s, (s < NUM_STAGES - 1) ? 1 : 0);
    }
}

// Round 13
// 1161.501 us; speedup vs baseline: 1.9280x; 1.1870x over previous
//
#include <hip/hip_runtime.h>
#include <math.h>

// Residual VQ, 4 stages, N=16384 rows, D=512, K=4096.
// Round 13: round-12 structure (PASSED, 1378us) with passC re-parallelized:
//   - CROWS 64->32, gridDim.y 16->64: ~1400 active blocks (was ~360) so the
//     batch tail no longer defines the runtime (occupancy was 10%).
//   - swizzle upgraded to s = d4 ^ ((cand>>2)&7) ^ ((cand>>5)&3): kills the
//     residual 4-way read conflict between lanes 8 apart (rows 32 apart).
// passA stays the round-9 verbatim kernel (98.7us; two attempted "upgrades"
// both regressed via spill/occupancy -- it is at its structural plateau).
// Exact-math invariants (verified rounds 3-12): one fmaf per d, d ascending,
// per output; epilogue fl(fl(rsq-fl(2*dot))+cbsq) uncontracted; first-index
// ties; numpy pairwise rsq/cbsq tree; exact residual/q_ste chain in combine.

namespace {
constexpr int N_ROWS     = 16384;
constexpr int DIM        = 512;
constexpr int K_CODES    = 4096;
constexpr int NUM_STAGES = 4;

constexpr int KTILES = 32;            // 128 codes per tile
constexpr int LTS    = 72;            // passA LDS row stride (bf16 elems)
constexpr float EPS  = 1e-3f;         // candidate margin (proven rounds 7-12)

constexpr int CROWS  = 32;            // passC rows per batch
constexpr int CGRIDY = 64;            // passC y-blocks per ktile
constexpr int WSTRC  = 68;            // passC Ws row stride (dwords)
constexpr int RSTR   = 68;            // passC Rs row stride (dwords)

// d_out layout (all read back as float32):
constexpr size_t Q_OFF    = 0;
constexpr size_t IDX_OFF  = (size_t)N_ROWS * DIM;                  // 8388608
constexpr size_t LOSS_OFF = IDX_OFF + (size_t)N_ROWS * NUM_STAGES; // 8454144

// ws layout (bytes), total ~56.2 MB:
constexpr size_t RES_OFF  = 0;                                    // 32 MB fp32 residual
constexpr size_t RH_OFF   = (size_t)N_ROWS * DIM * 4;             // +16 MB bf16 residual
constexpr size_t WH_OFF   = RH_OFF + (size_t)N_ROWS * DIM * 2;    // +4 MB bf16 codebook
constexpr size_t CBSQ_OFF = WH_OFF + (size_t)K_CODES * DIM * 2;   // +16 KB
constexpr size_t RSQ_OFF  = CBSQ_OFF + (size_t)K_CODES * 4;       // +64 KB
constexpr size_t PART_OFF = RSQ_OFF + (size_t)N_ROWS * 4;         // +2 MB tile mins
constexpr size_t BCNT_OFF = PART_OFF + (size_t)N_ROWS * KTILES * 4; // +128 B
constexpr size_t BENT_OFF = BCNT_OFF + 128;                       // +2 MB worklists
constexpr size_t BEST_OFF = BENT_OFF + (size_t)KTILES * N_ROWS * 4; // +128 KB packed best
} // namespace

typedef short bf16x8 __attribute__((ext_vector_type(8)));
typedef float f32x4  __attribute__((ext_vector_type(4)));

__device__ __forceinline__ unsigned short f2bf(float x) {   // RNE fp32->bf16
    unsigned int u = __float_as_uint(x);
    return (unsigned short)((u + 0x7fffu + ((u >> 16) & 1u)) >> 16);
}

__device__ __forceinline__ float f4c(const float4& v, int q) {
    return q == 0 ? v.x : q == 1 ? v.y : q == 2 ? v.z : v.w;
}

// Register-based exact pairwise tree: v8[i] = row[lane + i*64], i=0..7.
// Returns the numpy fp32 pairwise sum of squares on lane 0.
__device__ __forceinline__ float rowsq_tree(const float v8[8], int lane) {
#pragma clang fp contract(off)
    float P[4];
#pragma unroll
    for (int b = 0; b < 4; ++b) {
        float xa = v8[2 * b];          // elem b*128 + lane
        float xb = v8[2 * b + 1];      // elem b*128 + 64 + lane
        float sa = xa * xa;
        float sb = xb * xb;
        float R  = sa + sb;
        float t  = R + __shfl_down(R, 16, 64);
        float u  = t + __shfl_down(t, 32, 64);
        float a  = u + __shfl_down(u, 8, 64);
        float c  = a + __shfl_down(a, 4, 64);
        float d  = c + __shfl_down(c, 2, 64);
        P[b]     = d + __shfl_down(d, 1, 64);
    }
    float s01 = P[0] + P[1];
    float s23 = P[2] + P[3];
    return s01 + s23;
}

__global__ __launch_bounds__(64)
void cbsq_kernel(const float* __restrict__ cb, float* __restrict__ cb_sq,
                 float* __restrict__ loss) {
    int k = blockIdx.x;
    int lane = threadIdx.x;
    const float* row = cb + (size_t)k * DIM;
    float v8[8];
#pragma unroll
    for (int i = 0; i < 8; ++i) v8[i] = row[lane + i * 64];
    float s = rowsq_tree(v8, lane);
    if (lane == 0) cb_sq[k] = s;
    if (k == 0 && lane == 0) *loss = 0.0f;
}

// Stage-0 init: rh = bf16(input), rsq = pairwise(input), zero bcnt.
__global__ __launch_bounds__(256)
void init_kernel(const float* __restrict__ input,
                 unsigned short* __restrict__ rh,
                 float* __restrict__ rsq, int* __restrict__ bcnt) {
    const int t = threadIdx.x;
    if (blockIdx.x == 0 && t < KTILES) bcnt[t] = 0;
    const int lane = t & 63;
    const int sub  = t >> 6;
    const int row  = blockIdx.x * 4 + sub;
    const float* x = input + (size_t)row * DIM;
    unsigned short* rhp = rh + (size_t)row * DIM;
    float v8[8];
#pragma unroll
    for (int i = 0; i < 8; ++i) {
        int d = lane + i * 64;
        float v = x[d];
        v8[i] = v;
        rhp[d] = f2bf(v);
    }
    float s = rowsq_tree(v8, lane);
    if (lane == 0) rsq[row] = s;
}

// fp32 codebook -> bf16 (RNE), once per launch.
__global__ __launch_bounds__(256)
void whcvt_kernel(const float* __restrict__ cb, unsigned short* __restrict__ wh) {
    size_t i = ((size_t)blockIdx.x * 256 + threadIdx.x) * 8;
    float4 v0 = *(const float4*)(cb + i);
    float4 v1 = *(const float4*)(cb + i + 4);
    uint4 o;
    o.x = f2bf(v0.x) | ((unsigned)f2bf(v0.y) << 16);
    o.y = f2bf(v0.z) | ((unsigned)f2bf(v0.w) << 16);
    o.z = f2bf(v1.x) | ((unsigned)f2bf(v1.y) << 16);
    o.w = f2bf(v1.z) | ((unsigned)f2bf(v1.w) << 16);
    *(uint4*)(wh + i) = o;
}

// Pass A: 128x128x(BK=64) bf16 MFMA GEMM; per-(row, ktile) min of y^.
// ROUND-9 VERBATIM (98.7us, MfmaUtil 30%, VGPR 64, no spill).
__global__ __launch_bounds__(256, 2)
void passA_kernel(const unsigned short* __restrict__ rh,
                  const unsigned short* __restrict__ wh,
                  const float* __restrict__ cb_sq,
                  const float* __restrict__ rsq,
                  float* __restrict__ part) {
    const int jb = blockIdx.x;              // ktile (fast: share A-panel in L2)
    const int mb = blockIdx.y;
    const int mbase = mb * 128;
    const int nbase = jb * 128;

    __shared__ __align__(16) unsigned short At[128 * LTS];
    __shared__ __align__(16) unsigned short Bt[128 * LTS];
    __shared__ float rowmin[128][2];

    const int t    = threadIdx.x;
    const int lane = t & 63;
    const int wid  = t >> 6;
    const int wr   = wid >> 1;              // wave row (0/1)
    const int wc   = wid & 1;               // wave col (0/1)

    f32x4 acc[4][4];
#pragma unroll
    for (int mi = 0; mi < 4; ++mi)
#pragma unroll
        for (int ni = 0; ni < 4; ++ni) acc[mi][ni] = (f32x4){0.f, 0.f, 0.f, 0.f};

    for (int k0 = 0; k0 < DIM; k0 += 64) {
        // Stage A and B: each 128 rows x 64 d bf16 = 4 rounds x (16B ld + 16B st).
#pragma unroll
        for (int p = 0; p < 4; ++p) {
            int idx = p * 256 + t;
            int row = idx >> 3;
            int d8  = idx & 7;
            uint4 va = *(const uint4*)(rh + (size_t)(mbase + row) * DIM + k0 + d8 * 8);
            *(uint4*)&At[row * LTS + d8 * 8] = va;
            uint4 vb = *(const uint4*)(wh + (size_t)(nbase + row) * DIM + k0 + d8 * 8);
            *(uint4*)&Bt[row * LTS + d8 * 8] = vb;
        }
        __syncthreads();

#pragma unroll
        for (int kk = 0; kk < 2; ++kk) {
            bf16x8 af[4], bfr[4];
#pragma unroll
            for (int mi = 0; mi < 4; ++mi)
                af[mi] = *(const bf16x8*)&At[(wr * 64 + mi * 16 + (lane & 15)) * LTS
                                             + kk * 32 + (lane >> 4) * 8];
#pragma unroll
            for (int ni = 0; ni < 4; ++ni)
                bfr[ni] = *(const bf16x8*)&Bt[(wc * 64 + ni * 16 + (lane & 15)) * LTS
                                              + kk * 32 + (lane >> 4) * 8];
#pragma unroll
            for (int mi = 0; mi < 4; ++mi)
#pragma unroll
                for (int ni = 0; ni < 4; ++ni)
                    acc[mi][ni] = __builtin_amdgcn_mfma_f32_16x16x32_bf16(
                        af[mi], bfr[ni], acc[mi][ni], 0, 0, 0);
        }
        __syncthreads();
    }

    // Epilogue: y^ rounding-form, min over wave's 64 cols per row, cross-wave min.
#pragma unroll
    for (int mi = 0; mi < 4; ++mi) {
#pragma unroll
        for (int reg = 0; reg < 4; ++reg) {
            int rloc = wr * 64 + mi * 16 + (lane >> 4) * 4 + reg;
            float rsqv = rsq[mbase + rloc];
            float m = INFINITY;
#pragma unroll
            for (int ni = 0; ni < 4; ++ni) {
                int kg = nbase + wc * 64 + ni * 16 + (lane & 15);
                float y;
                {
#pragma clang fp contract(off)
                    float t2 = 2.0f * acc[mi][ni][reg];
                    float u  = rsqv - t2;
                    y        = u + cb_sq[kg];
                }
                m = fminf(m, y);
            }
#pragma unroll
            for (int off = 1; off < 16; off <<= 1)
                m = fminf(m, __shfl_xor(m, off, 64));
            if ((lane & 15) == 0) rowmin[rloc][wc] = m;
        }
    }
    __syncthreads();
    if (t < 128)
        part[(size_t)(mbase + t) * KTILES + jb] = fminf(rowmin[t][0], rowmin[t][1]);
}

// Pass B: per row, flag tiles within EPS of the global min; init best.
__global__ __launch_bounds__(256)
void passB_kernel(const float* __restrict__ part,
                  int* __restrict__ bcnt, int* __restrict__ bent,
                  unsigned long long* __restrict__ best) {
    int row = blockIdx.x * 256 + threadIdx.x;
    const float* p = part + (size_t)row * KTILES;
    float gmin = p[0];
#pragma unroll
    for (int j = 1; j < KTILES; ++j) gmin = fminf(gmin, p[j]);
    float thr = gmin + EPS;
    best[row] = ~0ull;
#pragma unroll
    for (int j = 0; j < KTILES; ++j) {
        if (p[j] <= thr) {
            int pos = atomicAdd(&bcnt[j], 1);
            bent[(size_t)j * N_ROWS + pos] = row;
        }
    }
}

// Pass C: exact recheck. 256 thr = 8 row-groups x 32 cand-groups; thread owns
// 4 rows x 4 cands. Ws row-major with XOR-swizzled float4 slots
// (s = d4 ^ ((cand>>2)&7) ^ ((cand>>5)&3)): conflict-free writes AND reads
// including the lanes-8-apart (rows-32-apart) aliasing.
// Chain order d = 0..511 ascending per pair -> bit-exact.
__global__ __launch_bounds__(256)
void passC_kernel(const float* __restrict__ res,
                  const float* __restrict__ cb,
                  const float* __restrict__ cb_sq,
                  const float* __restrict__ rsq,
                  const int* __restrict__ bcnt, const int* __restrict__ bent,
                  unsigned long long* __restrict__ best) {
    const int j   = blockIdx.x;             // ktile
    const int cnt = bcnt[j];
    const int t   = threadIdx.x;
    const int cg  = t & 31;                 // cands cg*4 .. cg*4+3
    const int rg  = t >> 5;                 // rows  rg*4 .. rg*4+3

    __shared__ __align__(16) float Ws[128 * WSTRC];   // 34.8 KB, swizzled
    __shared__ __align__(16) float Rs[CROWS * RSTR];  // 8.7 KB
    __shared__ int   rowl[CROWS];
    __shared__ float rsql[CROWS];

    for (int base = blockIdx.y * CROWS; base < cnt; base += gridDim.y * CROWS) {
        if (t < CROWS) {
            int e  = base + t;
            int rw = bent[(size_t)j * N_ROWS + (e < cnt ? e : cnt - 1)];
            rowl[t] = rw;
            rsql[t] = rsq[rw];
        }
        __syncthreads();
        const int nrows = min(CROWS, cnt - base);

        float acc[4][4];
#pragma unroll
        for (int ri = 0; ri < 4; ++ri)
#pragma unroll
            for (int q = 0; q < 4; ++q) acc[ri][q] = 0.0f;

        for (int d0 = 0; d0 < DIM; d0 += 64) {
            // Stage W: 128 cands x 64 d = 2048 float4 -> 8/thread, swizzled slot.
#pragma unroll
            for (int p = 0; p < 8; ++p) {
                int idx  = p * 256 + t;
                int cand = idx >> 4;
                int d4   = idx & 15;
                float4 v = *(const float4*)(cb + (size_t)(j * 128 + cand) * DIM + d0 + d4 * 4);
                int s = d4 ^ ((cand >> 2) & 7) ^ ((cand >> 5) & 3);
                *(float4*)&Ws[cand * WSTRC + s * 4] = v;
            }
            // Stage R: 32 rows x 64 d = 512 float4 -> 2/thread, row-major.
#pragma unroll
            for (int p = 0; p < 2; ++p) {
                int idx = p * 256 + t;
                int row = idx >> 4;
                int d4  = idx & 15;
                float4 v = *(const float4*)(res + (size_t)rowl[row] * DIM + d0 + d4 * 4);
                *(float4*)&Rs[row * RSTR + d4 * 4] = v;
            }
            __syncthreads();

            // 16 d-quads: per dq, 4 Ws reads (cand rows) + 4 Rs reads (broadcast).
#pragma unroll
            for (int dq = 0; dq < 16; ++dq) {
                const int s = dq ^ (cg & 7) ^ ((cg >> 3) & 3);  // cand>>2==cg, cand>>5==cg>>3
                float4 w4[4];
#pragma unroll
                for (int q = 0; q < 4; ++q)
                    w4[q] = *(const float4*)&Ws[(cg * 4 + q) * WSTRC + s * 4];
#pragma unroll
                for (int ri = 0; ri < 4; ++ri) {
                    float4 rf = *(const float4*)&Rs[(rg * 4 + ri) * RSTR + dq * 4];
#pragma unroll
                    for (int dd = 0; dd < 4; ++dd) {
                        float rv = f4c(rf, dd);
                        acc[ri][0] = fmaf(rv, f4c(w4[0], dd), acc[ri][0]);
                        acc[ri][1] = fmaf(rv, f4c(w4[1], dd), acc[ri][1]);
                        acc[ri][2] = fmaf(rv, f4c(w4[2], dd), acc[ri][2]);
                        acc[ri][3] = fmaf(rv, f4c(w4[3], dd), acc[ri][3]);
                    }
                }
            }
            __syncthreads();
        }

        // Epilogue: exact y, lexicographic (y,k) reduce over the 32 cand-lanes.
#pragma unroll
        for (int ri = 0; ri < 4; ++ri) {
            int rloc = rg * 4 + ri;
            float rsqv = rsql[rloc];
            float by = INFINITY; int bk = 0x7fffffff;
#pragma unroll
            for (int q = 0; q < 4; ++q) {
                int k = j * 128 + cg * 4 + q;
                float y;
                {
#pragma clang fp contract(off)
                    float t2 = 2.0f * acc[ri][q];
                    float u  = rsqv - t2;
                    y        = u + cb_sq[k];
                }
                if (y < by || (y == by && k < bk)) { by = y; bk = k; }
            }
#pragma unroll
            for (int off = 1; off < 32; off <<= 1) {   // cg = lane bits 0..4
                float ov = __shfl_xor(by, off, 64);
                int   oi = __shfl_xor(bk, off, 64);
                if (ov < by || (ov == by && oi < bk)) { by = ov; bk = oi; }
            }
            if (cg == 0 && rloc < nrows) {
                unsigned long long pk =
                    ((unsigned long long)__float_as_uint(by) << 32) |
                    (unsigned long long)(unsigned)bk;
                atomicMin(&best[rowl[rloc]], pk);
            }
        }
        __syncthreads();   // before next batch overwrites rowl/rsql
    }
}

// Combine: best index -> idx_out; exact fp32 residual/q_ste update; for the
// next stage also emit bf16 residual (rh), exact pairwise rsq, and zero bcnt.
__global__ __launch_bounds__(256)
void combine_kernel(float* __restrict__ res_out,
                    const float* __restrict__ res_in,
                    const float* __restrict__ cb,
                    const unsigned long long* __restrict__ best,
                    float* __restrict__ qout,
                    float* __restrict__ idx_out,
                    unsigned short* __restrict__ rh,
                    float* __restrict__ rsq,
                    int* __restrict__ bcnt,
                    int stage, int do_next) {
#pragma clang fp contract(off)
    const int t    = threadIdx.x;
    if (do_next && blockIdx.x == 0 && t < KTILES) bcnt[t] = 0;
    const int lane = t & 63;
    const int sub  = t >> 6;
    const int row  = blockIdx.x * 4 + sub;

    int bi = (int)(best[row] & 0xffffffffull);
    if (lane == 0) idx_out[(size_t)row * NUM_STAGES + stage] = (float)bi;

    const float* w   = cb + (size_t)bi * DIM;
    const float* rin = res_in + (size_t)row * DIM;
    float*       r   = res_out + (size_t)row * DIM;
    float*       q   = qout + (size_t)row * DIM;
    unsigned short* rhp = rh + (size_t)row * DIM;

    float rn8[8];
#pragma unroll
    for (int i = 0; i < DIM / 64; ++i) {
        int d = lane + i * 64;
        float wv = w[d];
        float rv = rin[d];
        float tq    = wv - rv;     // fl(q - r)
        float q_ste = rv + tq;     // fl(r + (q - r))
        float rn    = rv - q_ste;  // fl(r - q_ste)
        rn8[i] = rn;
        if (do_next) {
            r[d]   = rn;
            rhp[d] = f2bf(rn);
        }
        if (stage == 0) q[d] = q_ste;
        else            q[d] = q[d] + q_ste;   // stage-order fp32 accumulation
    }
    if (do_next) {
        float s = rowsq_tree(rn8, lane);
        if (lane == 0) rsq[row] = s;
    }
}

extern "C" void kernel_launch(void* const* d_in, const int* in_sizes, int n_in,
                              void* d_out, int out_size, void* d_ws, size_t ws_size,
                              hipStream_t stream) {
    const float* input = (const float*)d_in[0];
    const float* cb    = (const float*)d_in[1];

    float* out_f   = (float*)d_out;
    float* qout    = out_f + Q_OFF;
    float* idx_out = out_f + IDX_OFF;
    float* loss    = out_f + LOSS_OFF;

    char* ws = (char*)d_ws;
    float*          residual = (float*)(ws + RES_OFF);
    unsigned short* rh       = (unsigned short*)(ws + RH_OFF);
    unsigned short* wh       = (unsigned short*)(ws + WH_OFF);
    float*          cb_sq    = (float*)(ws + CBSQ_OFF);
    float*          rsq      = (float*)(ws + RSQ_OFF);
    float*          part     = (float*)(ws + PART_OFF);
    int*            bcnt     = (int*)(ws + BCNT_OFF);
    int*            bent     = (int*)(ws + BENT_OFF);
    unsigned long long* best = (unsigned long long*)(ws + BEST_OFF);

    whcvt_kernel<<<(K_CODES * DIM) / (256 * 8), 256, 0, stream>>>(cb, wh);
    cbsq_kernel<<<K_CODES, 64, 0, stream>>>(cb, cb_sq, loss);
    init_kernel<<<N_ROWS / 4, 256, 0, stream>>>(input, rh, rsq, bcnt);

    for (int s = 0; s < NUM_STAGES; ++s) {
        const float* rin = (s == 0) ? input : residual;
        passA_kernel<<<dim3(KTILES, N_ROWS / 128), 256, 0, stream>>>(
            rh, wh, cb_sq, rsq, part);
        passB_kernel<<<N_ROWS / 256, 256, 0, stream>>>(part, bcnt, bent, best);
        passC_kernel<<<dim3(KTILES, CGRIDY), 256, 0, stream>>>(
            rin, cb, cb_sq, rsq, bcnt, bent, best);
        combine_kernel<<<N_ROWS / 4, 256, 0, stream>>>(
            residual, rin, cb, best, qout, idx_out, rh, rsq, bcnt,
            s, (s < NUM_STAGES - 1) ? 1 : 0);
    }
}